// Round 10
// baseline (232.501 us; speedup 1.0000x reference)
//
#include <hip/hip_runtime.h>
#include <math.h>

#define EPS 1e-16f
#define SLOT 64
__device__ __forceinline__ float lrelu(float v) { return v > 0.0f ? v : 0.2f * v; }

// bf16 pack/unpack (RNE; inputs finite)
__device__ __forceinline__ unsigned short f2bf(float f) {
    unsigned u = __float_as_uint(f);
    u += 0x7FFF + ((u >> 16) & 1);
    return (unsigned short)(u >> 16);
}
__device__ __forceinline__ float bf2f(unsigned short s) {
    return __uint_as_float(((unsigned)s) << 16);
}

// ---------------- fused: slot-CSR scatter + layer-1 GEMM + w2-projection ----------
// Slot-CSR: node d's incoming-edge sources live at ssrc16[d*64 .. d*64+deg[d]) (ushort:
// src < 50000 < 2^16; halves slot lines -> typical node's ~16 slots fit ONE 64B line,
// improving scatter write-combining).
// Block roles: [0,D) scatter (8 edges/thread, 8 atomic chains); [D,D+G1) GEMM; D+G1 = the
// w2-projection block (w2s = W2 @ att_src2, w2d = W2 @ att_dst2; 64-vectors used by agg1's
// epilogue dots — this is what lets k_gemm2 be deleted via linearity:
// out = (sum alpha*xx) @ W2, a_src2 = xx . w2s).
// GEMM: x[N,128] @ W1[128,64] -> h1 (bf16) + per-head attention dots. K-split halves LDS
// to 33.3KB -> 4 blocks/CU. Pitch 65 (==1 mod 32) -> <=2-way conflicts.
#define LDP 65
__global__ __launch_bounds__(256, 4) void k_gemm1_scat(
    const float* __restrict__ x, const float* __restrict__ W1,
    const float* __restrict__ att_src1, const float* __restrict__ att_dst1,
    const float* __restrict__ W2, const float* __restrict__ att_src2,
    const float* __restrict__ att_dst2,
    unsigned short* __restrict__ h1b, float* __restrict__ a_src1, float* __restrict__ a_dst1,
    float* __restrict__ w2s, float* __restrict__ w2d,
    int N, int D, int G1, const int* __restrict__ src, const int* __restrict__ dst,
    int* __restrict__ deg, unsigned short* __restrict__ ssrc16, int E) {
    __shared__ float sX[64 * LDP];     // [m][k-half]  16.6KB
    __shared__ float sW[64 * LDP];     // [k-half][n]  16.6KB
    int t = threadIdx.x;
    if (blockIdx.x == D + G1) {                   // w2 projection (tiny)
        if (t < 64) {
            float s = 0.f, dd = 0.f;
            for (int j = 0; j < 40; j++) {
                float w = W2[t * 40 + j];
                s = fmaf(w, att_src2[j], s);
                dd = fmaf(w, att_dst2[j], dd);
            }
            w2s[t] = s; w2d[t] = dd;
        }
        return;
    }
    if (blockIdx.x < D) {
        int e0 = (blockIdx.x * 256 + t) * 8;
        if (e0 < E) {
            int4 sa = *((const int4*)(src + e0));
            int4 sb = *((const int4*)(src + e0 + 4));
            int4 da = *((const int4*)(dst + e0));
            int4 db = *((const int4*)(dst + e0 + 4));
            int p0 = atomicAdd(&deg[da.x], 1);
            int p1 = atomicAdd(&deg[da.y], 1);
            int p2 = atomicAdd(&deg[da.z], 1);
            int p3 = atomicAdd(&deg[da.w], 1);
            int p4 = atomicAdd(&deg[db.x], 1);
            int p5 = atomicAdd(&deg[db.y], 1);
            int p6 = atomicAdd(&deg[db.z], 1);
            int p7 = atomicAdd(&deg[db.w], 1);
            if (p0 < SLOT) ssrc16[(da.x << 6) + p0] = (unsigned short)sa.x;
            if (p1 < SLOT) ssrc16[(da.y << 6) + p1] = (unsigned short)sa.y;
            if (p2 < SLOT) ssrc16[(da.z << 6) + p2] = (unsigned short)sa.z;
            if (p3 < SLOT) ssrc16[(da.w << 6) + p3] = (unsigned short)sa.w;
            if (p4 < SLOT) ssrc16[(db.x << 6) + p4] = (unsigned short)sb.x;
            if (p5 < SLOT) ssrc16[(db.y << 6) + p5] = (unsigned short)sb.y;
            if (p6 < SLOT) ssrc16[(db.z << 6) + p6] = (unsigned short)sb.z;
            if (p7 < SLOT) ssrc16[(db.w << 6) + p7] = (unsigned short)sb.w;
        }
        return;
    }
    int r0 = (blockIdx.x - D) * 64;
    int tx = t & 15, ty = t >> 4;                // rows 4*tx.., cols 4*ty..
    float c[4][4] = {{0.f}};
#pragma unroll
    for (int kh = 0; kh < 2; kh++) {
        for (int i = t; i < 1024; i += 256) {    // stage W1 half: i = k*16 + n4
            int k = i >> 4, n4 = i & 15;
            float4 v = ((const float4*)W1)[(64 * kh + k) * 16 + n4];
            float* p = sW + k * LDP + 4 * n4;
            p[0] = v.x; p[1] = v.y; p[2] = v.z; p[3] = v.w;
        }
        for (int i = t; i < 1024; i += 256) {    // stage x half: i = m*16 + k4
            int m = i >> 4, k4 = i & 15;
            int r = r0 + m;
            float4 v = make_float4(0.f, 0.f, 0.f, 0.f);
            if (r < N) v = ((const float4*)(x + (size_t)r * 128))[16 * kh + k4];
            float* p = sX + m * LDP + 4 * k4;
            p[0] = v.x; p[1] = v.y; p[2] = v.z; p[3] = v.w;
        }
        __syncthreads();
        const float* pA = sX + 4 * tx * LDP;
        const float* pB = sW + 4 * ty;
#pragma unroll 8
        for (int k = 0; k < 64; k++) {
            float a0 = pA[k], a1 = pA[LDP + k], a2 = pA[2 * LDP + k], a3 = pA[3 * LDP + k];
            const float* pb = pB + k * LDP;
            float b0 = pb[0], b1 = pb[1], b2 = pb[2], b3 = pb[3];
            c[0][0] = fmaf(a0, b0, c[0][0]); c[0][1] = fmaf(a0, b1, c[0][1]);
            c[0][2] = fmaf(a0, b2, c[0][2]); c[0][3] = fmaf(a0, b3, c[0][3]);
            c[1][0] = fmaf(a1, b0, c[1][0]); c[1][1] = fmaf(a1, b1, c[1][1]);
            c[1][2] = fmaf(a1, b2, c[1][2]); c[1][3] = fmaf(a1, b3, c[1][3]);
            c[2][0] = fmaf(a2, b0, c[2][0]); c[2][1] = fmaf(a2, b1, c[2][1]);
            c[2][2] = fmaf(a2, b2, c[2][2]); c[2][3] = fmaf(a2, b3, c[2][3]);
            c[3][0] = fmaf(a3, b0, c[3][0]); c[3][1] = fmaf(a3, b1, c[3][1]);
            c[3][2] = fmaf(a3, b2, c[3][2]); c[3][3] = fmaf(a3, b3, c[3][3]);
        }
        __syncthreads();
    }
    // epilogue: h1 as bf16 + fused per-head attention dots
    float as0 = att_src1[4 * ty + 0], as1 = att_src1[4 * ty + 1],
          as2 = att_src1[4 * ty + 2], as3 = att_src1[4 * ty + 3];
    float ad0 = att_dst1[4 * ty + 0], ad1 = att_dst1[4 * ty + 1],
          ad2 = att_dst1[4 * ty + 2], ad3 = att_dst1[4 * ty + 3];
    float* sPs = sX;                              // [row][17]
    float* sPd = sX + 64 * 17;
#pragma unroll
    for (int i = 0; i < 4; i++) {
        int row = 4 * tx + i;
        int r = r0 + row;
        if (r < N) {
            ushort4 hv;
            hv.x = f2bf(c[i][0]); hv.y = f2bf(c[i][1]);
            hv.z = f2bf(c[i][2]); hv.w = f2bf(c[i][3]);
            *((ushort4*)(h1b + (size_t)r * 64 + 4 * ty)) = hv;
        }
        sPs[row * 17 + ty] = fmaf(c[i][0], as0, fmaf(c[i][1], as1, fmaf(c[i][2], as2, c[i][3] * as3)));
        sPd[row * 17 + ty] = fmaf(c[i][0], ad0, fmaf(c[i][1], ad1, fmaf(c[i][2], ad2, c[i][3] * ad3)));
    }
    __syncthreads();
    for (int i = t; i < 512; i += 256) {          // i = row*8 + h
        int row = i >> 3, h = i & 7;
        int r = r0 + row;
        if (r < N) {
            a_src1[r * 8 + h] = sPs[row * 17 + 2 * h] + sPs[row * 17 + 2 * h + 1];
            a_dst1[r * 8 + h] = sPd[row * 17 + 2 * h] + sPd[row * 17 + 2 * h + 1];
        }
    }
}

// ---------------- layer 1: per-dst softmax + aggregate + xxb/a2 epilogue (one wave/node) -----
// Dual-row gathers (round-7 form, best measured): lane loads a uint (2 bf16 cols); lanes
// 0-31 = row A, 32-63 = row B -> one instruction gathers TWO h1b rows. Epilogue: ELU'd
// row written as bf16 (xxb) + a_src2/a_dst2 via w2s/w2d dots (10 shuffles) — replaces the
// deleted k_gemm2's partial-dot machinery.
__global__ __launch_bounds__(256) void k_node_agg1(
    const int* __restrict__ deg, const unsigned short* __restrict__ ssrc16,
    const float* __restrict__ a_src1, const float* __restrict__ a_dst1,
    const unsigned short* __restrict__ h1b, const float* __restrict__ bias1,
    const float* __restrict__ w2s, const float* __restrict__ w2d,
    unsigned short* __restrict__ xxb, float* __restrict__ a_src2, float* __restrict__ a_dst2,
    int N) {
    int d = (blockIdx.x * 256 + threadIdx.x) >> 6;
    int lane = threadIdx.x & 63;
    if (d >= N) return;
    int start = d << 6;
    int m = min(deg[d], SLOT);                    // wave-uniform
    int h8 = lane & 7;      // head this lane covers in phase A
    int eoff = lane >> 3;   // edge-in-chunk this lane covers in phase A
    int q = lane & 31;      // col-pair index: cols 2q, 2q+1
    int hsel = q >> 2;      // head owning the col pair
    int sub = lane >> 5;    // 0: even edges-in-pair, 1: odd
    float adst8 = a_dst1[d * 8 + h8];
    int s_lane = 0;
    if (lane < m) s_lane = ssrc16[start + lane];
    int nch = (m + 7) >> 3;                       // 8-edge chunks
    // prime chunk-0 gathers
    unsigned rA[4];
#pragma unroll
    for (int k = 0; k < 4; k++) {
        int sR = __shfl(s_lane, 2 * k + sub);
        rA[k] = *((const unsigned*)(h1b + (size_t)sR * 64 + (q << 1)));
    }
    // phase A: per-edge logits, 8 edges x 8 heads in parallel
    float exv[8];
    float lsumA = 0.0f;
#pragma unroll
    for (int c = 0; c < 8; c++) {
        int idx = c * 8 + eoff;
        int s_c = __shfl(s_lane, idx);
        float e = 0.0f;
        if (idx < m) e = __expf(lrelu(a_src1[(size_t)s_c * 8 + h8] + adst8));
        exv[c] = e;
        lsumA += e;
    }
    // phase B: 2-deep pipelined chunks, 4 dual-row gathers per chunk
    float accLo = 0.0f, accHi = 0.0f;
#pragma unroll
    for (int c = 0; c < 8; c++) {
        if (c >= nch) break;                      // wave-uniform
        unsigned rB[4];
        if (c + 1 < nch) {
#pragma unroll
            for (int k = 0; k < 4; k++) {
                int sR = __shfl(s_lane, (c + 1) * 8 + 2 * k + sub);
                rB[k] = *((const unsigned*)(h1b + (size_t)sR * 64 + (q << 1)));
            }
        }
#pragma unroll
        for (int k = 0; k < 4; k++) {
            float f = __shfl(exv[c], ((2 * k + sub) << 3) | hsel);
            accLo = fmaf(f, bf2f((unsigned short)(rA[k] & 0xffff)), accLo);
            accHi = fmaf(f, bf2f((unsigned short)(rA[k] >> 16)), accHi);
        }
        if (c + 1 < nch) {
#pragma unroll
            for (int k = 0; k < 4; k++) rA[k] = rB[k];
        }
    }
    accLo += __shfl_xor(accLo, 32);
    accHi += __shfl_xor(accHi, 32);
    float t = lsumA;
    t += __shfl_xor(t, 8); t += __shfl_xor(t, 16); t += __shfl_xor(t, 32);
    float lsum = __shfl(t, hsel);
    float ps = 0.f, pd = 0.f;
    if (lane < 32) {
        float2 bz = ((const float2*)bias1)[q];
        float oLo = accLo / (lsum + EPS) + bz.x;
        float oHi = accHi / (lsum + EPS) + bz.y;
        oLo = oLo > 0.0f ? oLo : expm1f(oLo);     // ELU
        oHi = oHi > 0.0f ? oHi : expm1f(oHi);
        unsigned pk = ((unsigned)f2bf(oHi) << 16) | (unsigned)f2bf(oLo);
        *((unsigned*)(xxb + (size_t)d * 64 + 2 * q)) = pk;
        float2 ws2 = ((const float2*)w2s)[q];
        float2 wd2 = ((const float2*)w2d)[q];
        ps = fmaf(oLo, ws2.x, oHi * ws2.y);       // fp32 xx dots (pre-quantization)
        pd = fmaf(oLo, wd2.x, oHi * wd2.y);
    }
    // reduce over lanes 0-31 (offsets <=16 keep halves separate; lanes>=32 contribute 0)
    ps += __shfl_xor(ps, 1); ps += __shfl_xor(ps, 2); ps += __shfl_xor(ps, 4);
    ps += __shfl_xor(ps, 8); ps += __shfl_xor(ps, 16);
    pd += __shfl_xor(pd, 1); pd += __shfl_xor(pd, 2); pd += __shfl_xor(pd, 4);
    pd += __shfl_xor(pd, 8); pd += __shfl_xor(pd, 16);
    if (lane == 0) { a_src2[d] = ps; a_dst2[d] = pd; }
}

// ---------------- layer 2: aggregate xxb, THEN apply W2 (gemm2 deleted by linearity) ---------
// y[d] = (sum_e alpha_e * xxb[src_e]); out[d] = y @ W2 + bias2.
// Gathers use agg1's dual-row uint pattern on the 6.4MB xxb table (128B/row, 2 lines —
// less than h2's 160B/2.5 lines). GEMV tail: 32-step shuffle loop vs L1-hot W2 (10KB);
// no LDS, no barrier (round-4 lesson: don't add occupancy-poison to gather kernels).
__global__ __launch_bounds__(256) void k_node_agg2(
    const int* __restrict__ deg, const unsigned short* __restrict__ ssrc16,
    const float* __restrict__ a_src2, const float* __restrict__ a_dst2,
    const unsigned short* __restrict__ xxb, const float* __restrict__ W2,
    const float* __restrict__ bias2, float* __restrict__ out, int N) {
    int d = (blockIdx.x * 256 + threadIdx.x) >> 6;
    int lane = threadIdx.x & 63;
    if (d >= N) return;
    int start = d << 6;
    int m = min(deg[d], SLOT);                    // wave-uniform
    float adst = a_dst2[d];
    int s_lane = 0;
    if (lane < m) s_lane = ssrc16[start + lane];
    float ex_l = 0.0f;
    if (lane < m) ex_l = __expf(lrelu(a_src2[s_lane] + adst));
    float t = ex_l;
#pragma unroll
    for (int off = 32; off; off >>= 1) t += __shfl_xor(t, off);
    int q = lane & 31;                            // col-pair: cols 2q, 2q+1
    int sub = lane >> 5;                          // edge parity
    int nch = (m + 7) >> 3;
    unsigned rA[4];
#pragma unroll
    for (int k = 0; k < 4; k++) {
        int sR = __shfl(s_lane, 2 * k + sub);
        rA[k] = *((const unsigned*)(xxb + (size_t)sR * 64 + (q << 1)));
    }
    float accLo = 0.0f, accHi = 0.0f;
#pragma unroll
    for (int c = 0; c < 8; c++) {
        if (c >= nch) break;                      // wave-uniform
        unsigned rB[4];
        if (c + 1 < nch) {
#pragma unroll
            for (int k = 0; k < 4; k++) {
                int sR = __shfl(s_lane, (c + 1) * 8 + 2 * k + sub);
                rB[k] = *((const unsigned*)(xxb + (size_t)sR * 64 + (q << 1)));
            }
        }
#pragma unroll
        for (int k = 0; k < 4; k++) {
            float f = __shfl(ex_l, c * 8 + 2 * k + sub);
            accLo = fmaf(f, bf2f((unsigned short)(rA[k] & 0xffff)), accLo);
            accHi = fmaf(f, bf2f((unsigned short)(rA[k] >> 16)), accHi);
        }
        if (c + 1 < nch) {
#pragma unroll
            for (int k = 0; k < 4; k++) rA[k] = rB[k];
        }
    }
    accLo += __shfl_xor(accLo, 32);
    accHi += __shfl_xor(accHi, 32);
    float yLo = accLo / (t + EPS);                // lanes 0-31 hold y[2q], y[2q+1]
    float yHi = accHi / (t + EPS);
    // GEMV tail: lane j computes out[d][j] = y . W2[:,j] + bias2[j]
    int jj = lane < 40 ? lane : 39;               // clamp: idle lanes do safe loads
    float oj = bias2[jj];
#pragma unroll 8
    for (int l = 0; l < 32; l++) {
        float yl = __shfl(yLo, l);
        float yh = __shfl(yHi, l);
        oj = fmaf(yl, W2[(2 * l) * 40 + jj], oj);
        oj = fmaf(yh, W2[(2 * l + 1) * 40 + jj], oj);
    }
    if (lane < 40) out[(size_t)d * 40 + lane] = oj;
}

// ---------------- launch ----------------
extern "C" void kernel_launch(void* const* d_in, const int* in_sizes, int n_in,
                              void* d_out, int out_size, void* d_ws, size_t ws_size,
                              hipStream_t stream) {
    const float* x        = (const float*)d_in[0];
    const int*   ei       = (const int*)d_in[1];
    const float* W1       = (const float*)d_in[2];
    const float* att_src1 = (const float*)d_in[3];
    const float* att_dst1 = (const float*)d_in[4];
    const float* bias1    = (const float*)d_in[5];
    const float* W2       = (const float*)d_in[6];
    const float* att_src2 = (const float*)d_in[7];
    const float* att_dst2 = (const float*)d_in[8];
    const float* bias2    = (const float*)d_in[9];
    float* out = (float*)d_out;

    const int N = in_sizes[0] / 128;   // 50000
    const int E = in_sizes[1] / 2;     // 800000
    const int* src = ei;
    const int* dst = ei + E;

    // workspace layout (slot-CSR ushort; xxb bf16; h2/xx deleted — gemm2 folded away)
    float* ws = (float*)d_ws;
    size_t off = 0;
    int*            deg    = (int*)(ws + off);            off += (size_t)N;
    unsigned short* ssrc16 = (unsigned short*)(ws + off); off += (size_t)N * 32;  // N*64 u16
    unsigned short* h1b    = (unsigned short*)(ws + off); off += (size_t)N * 32;  // N*64 bf16
    float* a_src1 = ws + off; off += (size_t)N * 8;
    float* a_dst1 = ws + off; off += (size_t)N * 8;
    unsigned short* xxb    = (unsigned short*)(ws + off); off += (size_t)N * 32;  // N*64 bf16
    float* a_src2 = ws + off; off += (size_t)N;
    float* a_dst2 = ws + off; off += (size_t)N;
    float* w2s    = ws + off; off += 64;
    float* w2d    = ws + off; off += 64;

    const int B = 256;
    int G1 = (N + 63) / 64;               // gemm blocks (782)
    int D  = (E / 8 + 255) / 256;         // scatter blocks (8 edges/thread, 391)

    hipMemsetAsync(deg, 0, (size_t)N * sizeof(int), stream);
    // scatter + gemm1 + w2proj fused: scatter blocks first (critical path), GEMM
    // co-schedules behind atomic latency, w2proj is 1 extra block at the end
    k_gemm1_scat<<<D + G1 + 1, B, 0, stream>>>(x, W1, att_src1, att_dst1, W2, att_src2,
                                               att_dst2, h1b, a_src1, a_dst1, w2s, w2d,
                                               N, D, G1, src, dst, deg, ssrc16, E);
    k_node_agg1<<<(N + 3) / 4, B, 0, stream>>>(deg, ssrc16, a_src1, a_dst1, h1b, bias1,
                                               w2s, w2d, xxb, a_src2, a_dst2, N);
    k_node_agg2<<<(N + 3) / 4, B, 0, stream>>>(deg, ssrc16, a_src2, a_dst2, xxb, W2,
                                               bias2, out, N);
}

// Round 11
// 216.389 us; speedup vs baseline: 1.0745x; 1.0745x over previous
//
#include <hip/hip_runtime.h>
#include <math.h>

#define EPS 1e-16f
#define SLOT 64
__device__ __forceinline__ float lrelu(float v) { return v > 0.0f ? v : 0.2f * v; }

// bf16 pack/unpack (RNE; inputs finite)
__device__ __forceinline__ unsigned short f2bf(float f) {
    unsigned u = __float_as_uint(f);
    u += 0x7FFF + ((u >> 16) & 1);
    return (unsigned short)(u >> 16);
}
__device__ __forceinline__ float bf2f(unsigned short s) {
    return __uint_as_float(((unsigned)s) << 16);
}

// ---------------- phase 1: bin edges by dst&7 into 8 XCD buckets ----------------
// Edge packed as (dst16<<16)|src16 (both < 50000 < 2^16) -> 4B/edge, 3.2MB total.
// Block-local LDS counts -> one global atomicAdd per partition per block (reserve) ->
// coalesced-ish writes (each block's per-partition group is a contiguous ~1KB chunk).
__global__ __launch_bounds__(256) void k_bin(
    const int* __restrict__ src, const int* __restrict__ dst,
    unsigned* __restrict__ bucket, int* __restrict__ cnt, int E, int CAP) {
    __shared__ int lcnt[8];
    __shared__ int lbase[8];
    int t = threadIdx.x;
    if (t < 8) lcnt[t] = 0;
    __syncthreads();
    int e0 = (blockIdx.x * 256 + t) * 8;
    unsigned pk[8]; int pos[8]; int pp[8];
    bool act = e0 < E;                            // E%8==0: whole 8-group valid
    if (act) {
        int4 sa = *((const int4*)(src + e0));
        int4 sb = *((const int4*)(src + e0 + 4));
        int4 da = *((const int4*)(dst + e0));
        int4 db = *((const int4*)(dst + e0 + 4));
        int s[8] = {sa.x, sa.y, sa.z, sa.w, sb.x, sb.y, sb.z, sb.w};
        int d_[8] = {da.x, da.y, da.z, da.w, db.x, db.y, db.z, db.w};
#pragma unroll
        for (int i = 0; i < 8; i++) {
            pp[i] = d_[i] & 7;
            pk[i] = ((unsigned)d_[i] << 16) | (unsigned)s[i];
            pos[i] = atomicAdd(&lcnt[pp[i]], 1);
        }
    }
    __syncthreads();
    if (t < 8) lbase[t] = atomicAdd(&cnt[t], lcnt[t]);
    __syncthreads();
    if (act) {
#pragma unroll
        for (int i = 0; i < 8; i++) {
            int idx = lbase[pp[i]] + pos[i];
            if (idx < CAP) bucket[(size_t)pp[i] * CAP + idx] = pk[i];
        }
    }
}

// ---------------- fused: XCD-local slot-CSR scatter (blocks [0,S)) + layer-1 GEMM ----------
// scat2 block b serves partition g=b&7 -> lands on XCD g (round-robin dispatch; perf-only).
// Partition g's degP slice [g*PAL, g*PAL+N/8) (25KB, PAL 64B-aligned -> no cross-partition
// line sharing) and its ssrc rows (every-8th 256B row) are touched by ONE XCD: atomics run
// in the local L2 with no line migration; slot stores write-combine. Bucket reads coalesced.
// GEMM blocks [S, S+G1): x[N,128] @ W1[128,64] -> h1 (bf16) + per-head attention dots.
// K-split halves LDS to 33.3KB -> 4 blocks/CU. Pitch 65 (==1 mod 32) -> <=2-way conflicts.
#define LDP 65
__global__ __launch_bounds__(256, 4) void k_gemm1_scat(
    const float* __restrict__ x, const float* __restrict__ W1,
    const float* __restrict__ att_src1, const float* __restrict__ att_dst1,
    unsigned short* __restrict__ h1b, float* __restrict__ a_src1, float* __restrict__ a_dst1,
    int N, int S, const unsigned* __restrict__ bucket, const int* __restrict__ cnt,
    int CAP, int PAL, int* __restrict__ degP, int* __restrict__ ssrc) {
    __shared__ float sX[64 * LDP];     // [m][k-half]  16.6KB
    __shared__ float sW[64 * LDP];     // [k-half][n]  16.6KB
    int t = threadIdx.x;
    if (blockIdx.x < S) {
        int g = blockIdx.x & 7;                   // -> XCD g
        int j = blockIdx.x >> 3;                  // block-in-group
        int cn = min(cnt[g], CAP);
        int stride = (S >> 3) * 256 * 8;
        const unsigned* bk = bucket + (size_t)g * CAP;
        int* dg = degP + (size_t)g * PAL;
        for (int base = (j * 256 + t) * 8; base < cn; base += stride) {
            if (base + 8 <= cn) {
                uint4 a = *((const uint4*)(bk + base));
                uint4 b = *((const uint4*)(bk + base + 4));
                unsigned e[8] = {a.x, a.y, a.z, a.w, b.x, b.y, b.z, b.w};
                int p[8];
#pragma unroll
                for (int i = 0; i < 8; i++) p[i] = atomicAdd(&dg[(e[i] >> 16) >> 3], 1);
#pragma unroll
                for (int i = 0; i < 8; i++) {
                    int dd = e[i] >> 16, ss = e[i] & 0xffff;
                    if (p[i] < SLOT) ssrc[((size_t)dd << 6) + p[i]] = ss;
                }
            } else {
                for (int i = base; i < cn; i++) {
                    unsigned e = bk[i];
                    int dd = e >> 16, ss = e & 0xffff;
                    int p = atomicAdd(&dg[dd >> 3], 1);
                    if (p < SLOT) ssrc[((size_t)dd << 6) + p] = ss;
                }
            }
        }
        return;
    }
    int r0 = (blockIdx.x - S) * 64;
    int tx = t & 15, ty = t >> 4;                // rows 4*tx.., cols 4*ty..
    float c[4][4] = {{0.f}};
#pragma unroll
    for (int kh = 0; kh < 2; kh++) {
        for (int i = t; i < 1024; i += 256) {    // stage W1 half: i = k*16 + n4
            int k = i >> 4, n4 = i & 15;
            float4 v = ((const float4*)W1)[(64 * kh + k) * 16 + n4];
            float* p = sW + k * LDP + 4 * n4;
            p[0] = v.x; p[1] = v.y; p[2] = v.z; p[3] = v.w;
        }
        for (int i = t; i < 1024; i += 256) {    // stage x half: i = m*16 + k4
            int m = i >> 4, k4 = i & 15;
            int r = r0 + m;
            float4 v = make_float4(0.f, 0.f, 0.f, 0.f);
            if (r < N) v = ((const float4*)(x + (size_t)r * 128))[16 * kh + k4];
            float* p = sX + m * LDP + 4 * k4;
            p[0] = v.x; p[1] = v.y; p[2] = v.z; p[3] = v.w;
        }
        __syncthreads();
        const float* pA = sX + 4 * tx * LDP;
        const float* pB = sW + 4 * ty;
#pragma unroll 8
        for (int k = 0; k < 64; k++) {
            float a0 = pA[k], a1 = pA[LDP + k], a2 = pA[2 * LDP + k], a3 = pA[3 * LDP + k];
            const float* pb = pB + k * LDP;
            float b0 = pb[0], b1 = pb[1], b2 = pb[2], b3 = pb[3];
            c[0][0] = fmaf(a0, b0, c[0][0]); c[0][1] = fmaf(a0, b1, c[0][1]);
            c[0][2] = fmaf(a0, b2, c[0][2]); c[0][3] = fmaf(a0, b3, c[0][3]);
            c[1][0] = fmaf(a1, b0, c[1][0]); c[1][1] = fmaf(a1, b1, c[1][1]);
            c[1][2] = fmaf(a1, b2, c[1][2]); c[1][3] = fmaf(a1, b3, c[1][3]);
            c[2][0] = fmaf(a2, b0, c[2][0]); c[2][1] = fmaf(a2, b1, c[2][1]);
            c[2][2] = fmaf(a2, b2, c[2][2]); c[2][3] = fmaf(a2, b3, c[2][3]);
            c[3][0] = fmaf(a3, b0, c[3][0]); c[3][1] = fmaf(a3, b1, c[3][1]);
            c[3][2] = fmaf(a3, b2, c[3][2]); c[3][3] = fmaf(a3, b3, c[3][3]);
        }
        __syncthreads();
    }
    // epilogue: h1 as bf16 + fused per-head attention dots
    float as0 = att_src1[4 * ty + 0], as1 = att_src1[4 * ty + 1],
          as2 = att_src1[4 * ty + 2], as3 = att_src1[4 * ty + 3];
    float ad0 = att_dst1[4 * ty + 0], ad1 = att_dst1[4 * ty + 1],
          ad2 = att_dst1[4 * ty + 2], ad3 = att_dst1[4 * ty + 3];
    float* sPs = sX;                              // [row][17]
    float* sPd = sX + 64 * 17;
#pragma unroll
    for (int i = 0; i < 4; i++) {
        int row = 4 * tx + i;
        int r = r0 + row;
        if (r < N) {
            ushort4 hv;
            hv.x = f2bf(c[i][0]); hv.y = f2bf(c[i][1]);
            hv.z = f2bf(c[i][2]); hv.w = f2bf(c[i][3]);
            *((ushort4*)(h1b + (size_t)r * 64 + 4 * ty)) = hv;
        }
        sPs[row * 17 + ty] = fmaf(c[i][0], as0, fmaf(c[i][1], as1, fmaf(c[i][2], as2, c[i][3] * as3)));
        sPd[row * 17 + ty] = fmaf(c[i][0], ad0, fmaf(c[i][1], ad1, fmaf(c[i][2], ad2, c[i][3] * ad3)));
    }
    __syncthreads();
    for (int i = t; i < 512; i += 256) {          // i = row*8 + h
        int row = i >> 3, h = i & 7;
        int r = r0 + row;
        if (r < N) {
            a_src1[r * 8 + h] = sPs[row * 17 + 2 * h] + sPs[row * 17 + 2 * h + 1];
            a_dst1[r * 8 + h] = sPd[row * 17 + 2 * h] + sPd[row * 17 + 2 * h + 1];
        }
    }
}

// ---------------- layer 1: per-dst-node softmax + aggregate (one wave per node) ----------------
// (round-7/9 dual-row form — best measured) Dual-row gathers: lane loads a uint (2 bf16
// cols); lanes 0-31 = row A, 32-63 = row B -> one instruction gathers TWO h1b rows.
// deg in partition-major degP[(d&7)*PAL + (d>>3)].
__global__ __launch_bounds__(256) void k_node_agg1(
    const int* __restrict__ degP, int PAL, const int* __restrict__ ssrc,
    const float* __restrict__ a_src1, const float* __restrict__ a_dst1,
    const unsigned short* __restrict__ h1b, const float* __restrict__ bias1,
    float* __restrict__ xx, int N) {
    int d = (blockIdx.x * 256 + threadIdx.x) >> 6;
    int lane = threadIdx.x & 63;
    if (d >= N) return;
    int start = d << 6;
    int m = min(degP[(size_t)(d & 7) * PAL + (d >> 3)], SLOT);   // wave-uniform
    int h8 = lane & 7;      // head this lane covers in phase A
    int eoff = lane >> 3;   // edge-in-chunk this lane covers in phase A
    int q = lane & 31;      // col-pair index: cols 2q, 2q+1
    int hsel = q >> 2;      // head owning the col pair
    int sub = lane >> 5;    // 0: even edges-in-pair, 1: odd
    float adst8 = a_dst1[d * 8 + h8];
    int s_lane = 0;
    if (lane < m) s_lane = ssrc[start + lane];
    int nch = (m + 7) >> 3;                       // 8-edge chunks
    // prime chunk-0 gathers (4 dual-row uint loads), fly under phase A
    unsigned rA[4];
#pragma unroll
    for (int k = 0; k < 4; k++) {
        int sR = __shfl(s_lane, 2 * k + sub);
        rA[k] = *((const unsigned*)(h1b + (size_t)sR * 64 + (q << 1)));
    }
    // phase A: per-edge logits, 8 edges x 8 heads in parallel
    float exv[8];
    float lsumA = 0.0f;
#pragma unroll
    for (int c = 0; c < 8; c++) {
        int idx = c * 8 + eoff;
        int s_c = __shfl(s_lane, idx);
        float e = 0.0f;
        if (idx < m) e = __expf(lrelu(a_src1[(size_t)s_c * 8 + h8] + adst8));
        exv[c] = e;
        lsumA += e;
    }
    // phase B: 2-deep pipelined chunks, 4 dual-row gathers per chunk
    float accLo = 0.0f, accHi = 0.0f;
#pragma unroll
    for (int c = 0; c < 8; c++) {
        if (c >= nch) break;                      // wave-uniform
        unsigned rB[4];
        if (c + 1 < nch) {
#pragma unroll
            for (int k = 0; k < 4; k++) {
                int sR = __shfl(s_lane, (c + 1) * 8 + 2 * k + sub);
                rB[k] = *((const unsigned*)(h1b + (size_t)sR * 64 + (q << 1)));
            }
        }
#pragma unroll
        for (int k = 0; k < 4; k++) {
            float f = __shfl(exv[c], ((2 * k + sub) << 3) | hsel);
            accLo = fmaf(f, bf2f((unsigned short)(rA[k] & 0xffff)), accLo);
            accHi = fmaf(f, bf2f((unsigned short)(rA[k] >> 16)), accHi);
        }
        if (c + 1 < nch) {
#pragma unroll
            for (int k = 0; k < 4; k++) rA[k] = rB[k];
        }
    }
    accLo += __shfl_xor(accLo, 32);
    accHi += __shfl_xor(accHi, 32);
    float t = lsumA;
    t += __shfl_xor(t, 8); t += __shfl_xor(t, 16); t += __shfl_xor(t, 32);
    float lsum = __shfl(t, hsel);
    if (lane < 32) {
        float2 bz = ((const float2*)bias1)[q];
        float oLo = accLo / (lsum + EPS) + bz.x;
        float oHi = accHi / (lsum + EPS) + bz.y;
        oLo = oLo > 0.0f ? oLo : expm1f(oLo);     // ELU
        oHi = oHi > 0.0f ? oHi : expm1f(oHi);
        *((float2*)(xx + (size_t)d * 64 + 2 * q)) = make_float2(oLo, oHi);
    }
}

// ---------------- layer 2 GEMM: xx[N,64] @ W2[64,40] -> h2, + fused attention dots ----
#define LDK2 65
#define LDN2 41
__global__ __launch_bounds__(256, 2) void k_gemm2(
    const float* __restrict__ xx, const float* __restrict__ W2,
    const float* __restrict__ att_src2, const float* __restrict__ att_dst2,
    float* __restrict__ h2, float* __restrict__ a_src2, float* __restrict__ a_dst2, int N) {
    __shared__ float sX[64 * LDK2];    // [m][k]
    __shared__ float sW[64 * LDN2];    // [k][n]
    int t = threadIdx.x;
    int r0 = blockIdx.x * 64;
    for (int i = t; i < 640; i += 256) {          // i = k*10 + n4
        int k = i / 10, n4 = i - k * 10;
        float4 v = ((const float4*)W2)[i];
        float* p = sW + k * LDN2 + 4 * n4;
        p[0] = v.x; p[1] = v.y; p[2] = v.z; p[3] = v.w;
    }
    for (int i = t; i < 1024; i += 256) {         // i = m*16 + k4
        int m = i >> 4, k4 = i & 15;
        int r = r0 + m;
        float4 v = make_float4(0.f, 0.f, 0.f, 0.f);
        if (r < N) v = ((const float4*)(xx + (size_t)r * 64))[k4];
        float* p = sX + m * LDK2 + 4 * k4;
        p[0] = v.x; p[1] = v.y; p[2] = v.z; p[3] = v.w;
    }
    __syncthreads();
    int tx = t & 15, ty = t >> 4;
    bool act = ty < 10;
    float c[4][4] = {{0.f}};
    if (act) {
        const float* pA = sX + 4 * tx * LDK2;
        const float* pB = sW + 4 * ty;
#pragma unroll 8
        for (int k = 0; k < 64; k++) {
            float a0 = pA[k], a1 = pA[LDK2 + k], a2 = pA[2 * LDK2 + k], a3 = pA[3 * LDK2 + k];
            const float* pb = pB + k * LDN2;
            float b0 = pb[0], b1 = pb[1], b2 = pb[2], b3 = pb[3];
            c[0][0] = fmaf(a0, b0, c[0][0]); c[0][1] = fmaf(a0, b1, c[0][1]);
            c[0][2] = fmaf(a0, b2, c[0][2]); c[0][3] = fmaf(a0, b3, c[0][3]);
            c[1][0] = fmaf(a1, b0, c[1][0]); c[1][1] = fmaf(a1, b1, c[1][1]);
            c[1][2] = fmaf(a1, b2, c[1][2]); c[1][3] = fmaf(a1, b3, c[1][3]);
            c[2][0] = fmaf(a2, b0, c[2][0]); c[2][1] = fmaf(a2, b1, c[2][1]);
            c[2][2] = fmaf(a2, b2, c[2][2]); c[2][3] = fmaf(a2, b3, c[2][3]);
            c[3][0] = fmaf(a3, b0, c[3][0]); c[3][1] = fmaf(a3, b1, c[3][1]);
            c[3][2] = fmaf(a3, b2, c[3][2]); c[3][3] = fmaf(a3, b3, c[3][3]);
        }
    }
    float as0 = 0.f, as1 = 0.f, as2 = 0.f, as3 = 0.f;
    float ad0 = 0.f, ad1 = 0.f, ad2 = 0.f, ad3 = 0.f;
    if (act) {
        as0 = att_src2[4 * ty + 0]; as1 = att_src2[4 * ty + 1];
        as2 = att_src2[4 * ty + 2]; as3 = att_src2[4 * ty + 3];
        ad0 = att_dst2[4 * ty + 0]; ad1 = att_dst2[4 * ty + 1];
        ad2 = att_dst2[4 * ty + 2]; ad3 = att_dst2[4 * ty + 3];
    }
    __syncthreads();                              // reuse sX as partials [row][11]
    float* sPs = sX;
    float* sPd = sX + 64 * 11;
#pragma unroll
    for (int i = 0; i < 4; i++) {
        int row = 4 * tx + i;
        int r = r0 + row;
        if (act) {
            if (r < N) {
                float4 hv = make_float4(c[i][0], c[i][1], c[i][2], c[i][3]);
                *((float4*)(h2 + (size_t)r * 40 + 4 * ty)) = hv;
            }
            sPs[row * 11 + ty] = fmaf(c[i][0], as0, fmaf(c[i][1], as1, fmaf(c[i][2], as2, c[i][3] * as3)));
            sPd[row * 11 + ty] = fmaf(c[i][0], ad0, fmaf(c[i][1], ad1, fmaf(c[i][2], ad2, c[i][3] * ad3)));
        }
    }
    __syncthreads();
    if (t < 64) {
        int r = r0 + t;
        if (r < N) {
            float ps = 0.f, pd = 0.f;
#pragma unroll
            for (int j = 0; j < 10; j++) {
                ps += sPs[t * 11 + j];
                pd += sPd[t * 11 + j];
            }
            a_src2[r] = ps;
            a_dst2[r] = pd;
        }
    }
}

// ---------------- layer 2: per-dst-node softmax + aggregate ----------------
// Triple-row gathers: each lane loads a float2 (2 cols of a 40-col h2 row); 20 lanes/row ->
// one instruction covers THREE rows. Gather instruction count -> m/3.
__global__ __launch_bounds__(256) void k_node_agg2(
    const int* __restrict__ degP, int PAL, const int* __restrict__ ssrc,
    const float* __restrict__ a_src2, const float* __restrict__ a_dst2,
    const float* __restrict__ h2, const float* __restrict__ bias2,
    float* __restrict__ out, int N) {
    int d = (blockIdx.x * 256 + threadIdx.x) >> 6;
    int lane = threadIdx.x & 63;
    if (d >= N) return;
    int start = d << 6;
    int m = min(degP[(size_t)(d & 7) * PAL + (d >> 3)], SLOT);   // wave-uniform
    float adst = a_dst2[d];
    int s_l = 0; float ex_l = 0.0f;
    if (lane < m) {
        s_l = ssrc[start + lane];
        ex_l = __expf(lrelu(a_src2[s_l] + adst));
    }
    int grp = lane / 20;                          // 0,1,2 gather groups; 3 = idle lanes
    int q20 = lane - grp * 20;                    // col-pair index within row
    bool gact = grp < 3;
    int nin = (m + 2) / 3;                        // gather instructions
    int nblk = (nin + 3) >> 2;                    // blocks of 4 instructions (<=6)
    float aLo = 0.0f, aHi = 0.0f;
    auto loadb = [&](int b, float2* g, float* f) {
#pragma unroll
        for (int k2 = 0; k2 < 4; k2++) {
            int j = 3 * (4 * b + k2) + grp;       // edge index
            int jm = j & 63;                      // clamp for shuffle validity
            int sR = __shfl(s_l, jm);
            float fv = __shfl(ex_l, jm);
            f[k2] = (gact && j < m) ? fv : 0.0f;
            g[k2] = *((const float2*)(h2 + (size_t)sR * 40 + 2 * q20));
        }
    };
    float2 gA[4]; float fA[4];
    if (nblk > 0) loadb(0, gA, fA);
#pragma unroll
    for (int b = 0; b < 6; b++) {
        if (b >= nblk) break;                     // wave-uniform
        float2 gB[4]; float fB[4];
        if (b + 1 < nblk) loadb(b + 1, gB, fB);
#pragma unroll
        for (int k2 = 0; k2 < 4; k2++) {
            aLo = fmaf(fA[k2], gA[k2].x, aLo);
            aHi = fmaf(fA[k2], gA[k2].y, aHi);
        }
        if (b + 1 < nblk) {
#pragma unroll
            for (int k2 = 0; k2 < 4; k2++) { gA[k2] = gB[k2]; fA[k2] = fB[k2]; }
        }
    }
    // merge the 3 edge groups (lanes l, l+20, l+40 hold the same col pair)
    int i1 = (lane + 20) & 63, i2 = (lane + 40) & 63;
    float ml1 = __shfl(aLo, i1), ml2 = __shfl(aLo, i2);
    float mh1 = __shfl(aHi, i1), mh2 = __shfl(aHi, i2);
    aLo += ml1 + ml2;
    aHi += mh1 + mh2;
    float t = ex_l;
#pragma unroll
    for (int off = 32; off; off >>= 1) t += __shfl_xor(t, off);
    if (lane < 20) {
        float2 bz = ((const float2*)bias2)[lane];
        float oLo = aLo / (t + EPS) + bz.x;
        float oHi = aHi / (t + EPS) + bz.y;
        *((float2*)(out + (size_t)d * 40 + 2 * lane)) = make_float2(oLo, oHi);
    }
}

// ---------------- launch ----------------
extern "C" void kernel_launch(void* const* d_in, const int* in_sizes, int n_in,
                              void* d_out, int out_size, void* d_ws, size_t ws_size,
                              hipStream_t stream) {
    const float* x        = (const float*)d_in[0];
    const int*   ei       = (const int*)d_in[1];
    const float* W1       = (const float*)d_in[2];
    const float* att_src1 = (const float*)d_in[3];
    const float* att_dst1 = (const float*)d_in[4];
    const float* bias1    = (const float*)d_in[5];
    const float* W2       = (const float*)d_in[6];
    const float* att_src2 = (const float*)d_in[7];
    const float* att_dst2 = (const float*)d_in[8];
    const float* bias2    = (const float*)d_in[9];
    float* out = (float*)d_out;

    const int N = in_sizes[0] / 128;   // 50000
    const int E = in_sizes[1] / 2;     // 800000
    const int* src = ei;
    const int* dst = ei + E;

    const int PAL = (((N + 7) / 8) + 15) & ~15;   // partition stride, 64B-aligned (6256)
    const int CAP = E / 8 + 65536;                // bucket capacity (>200 sigma slack)

    // workspace layout
    float* ws = (float*)d_ws;
    size_t off = 0;
    int*      degP   = (int*)(ws + off);      off += (size_t)8 * PAL;   // partition-major deg
    int*      cnt    = (int*)(ws + off);      off += 8;                 // bucket counters
    int*      ssrc   = (int*)(ws + off);      off += (size_t)N * SLOT;  // slot-CSR
    unsigned* bucket = (unsigned*)(ws + off); off += (size_t)8 * CAP;   // packed edges
    unsigned short* h1b = (unsigned short*)(ws + off); off += (size_t)N * 32;  // bf16 N*64
    float* a_src1 = ws + off; off += (size_t)N * 8;
    float* a_dst1 = ws + off; off += (size_t)N * 8;
    float* xx     = ws + off; off += (size_t)N * 64;
    float* h2     = ws + off; off += (size_t)N * 40;
    float* a_src2 = ws + off; off += (size_t)N;
    float* a_dst2 = ws + off; off += (size_t)N;

    const int B = 256;
    int G1 = (N + 63) / 64;               // gemm blocks (782)
    int NBIN = (E / 8 + 255) / 256;       // bin blocks (391)
    int S = 128;                          // scat2 blocks: 16 per XCD group

    hipMemsetAsync(degP, 0, ((size_t)8 * PAL + 8) * sizeof(int), stream);
    k_bin<<<NBIN, B, 0, stream>>>(src, dst, bucket, cnt, E, CAP);
    // XCD-local scatter + gemm1 fused: scat2 blocks first (critical path), GEMM
    // co-schedules behind atomic latency
    k_gemm1_scat<<<S + G1, B, 0, stream>>>(x, W1, att_src1, att_dst1, h1b, a_src1, a_dst1,
                                           N, S, bucket, cnt, CAP, PAL, degP, ssrc);
    k_node_agg1<<<(N + 3) / 4, B, 0, stream>>>(degP, PAL, ssrc, a_src1, a_dst1, h1b, bias1,
                                               xx, N);
    k_gemm2<<<G1, B, 0, stream>>>(xx, W2, att_src2, att_dst2, h2, a_src2, a_dst2, N);
    k_node_agg2<<<(N + 3) / 4, B, 0, stream>>>(degP, PAL, ssrc, a_src2, a_dst2, h2, bias2,
                                               out, N);
}